// Round 7
// baseline (262.260 us; speedup 1.0000x reference)
//
#include <hip/hip_runtime.h>
#include <hip/hip_bf16.h>
#include <hip/hip_fp16.h>

// ============================================================================
// GCN forward. CSR-by-dst via two-level bucketed counting sort; then
// SPLIT gather/dense pipeline:
//   - gather kernels: 4 lanes per node (edge-split), butterfly combine via
//     __shfl_xor, zero LDS, low VGPR -> pure memory-parallel gather.
//   - dense kernels: 1 lane per node, weights at wave-uniform global
//     addresses (-> s_load / SGPR operands, no LDS), streaming float4 I/O.
//
// Algebra: A_hat(xW) = (A_hat x)W, normalization factored as
//   out[d] = dinv[d] * ( sum_{s in N(d)} hs[s] + hs[d] ) + b,  hs = h*dinv[row]
// hs tables fp16 (xs=4.8MB, h2s=6.4MB, h3s=3.2MB, h4s=0.4MB); aggregate
// intermediates fp32 (shared 12.8MB buffer, disjoint lifetimes).
// ============================================================================

#define NBUCK_SHIFT 8            // 256 nodes per bucket
#define PART_CHUNK  4096         // edges per partition block (256 thr x 16)

// ---------------- pass A: bucket histogram ----------------
__global__ __launch_bounds__(256) void hist_kernel(const int* __restrict__ dst,
                                                   int* __restrict__ hist,
                                                   int n_edges, int nbuck) {
    __shared__ int h[512];
    for (int i = threadIdx.x; i < 512; i += 256) h[i] = 0;
    __syncthreads();
    for (long long e = (long long)blockIdx.x * 256 + threadIdx.x; e < n_edges;
         e += (long long)gridDim.x * 256)
        atomicAdd(&h[dst[e] >> NBUCK_SHIFT], 1);
    __syncthreads();
    for (int i = threadIdx.x; i < nbuck; i += 256)
        if (h[i]) atomicAdd(&hist[i], h[i]);
}

// ---------------- pass A': scan bucket sizes (single block) ----------------
__global__ void scan_hist_kernel(const int* __restrict__ hist, int* __restrict__ base,
                                 int* __restrict__ gcur, int nbuck, int total) {
    __shared__ int s[512];
    int v = (threadIdx.x < nbuck) ? hist[threadIdx.x] : 0;
    s[threadIdx.x] = v;
    __syncthreads();
    for (int off = 1; off < 512; off <<= 1) {
        int t = (threadIdx.x >= off) ? s[threadIdx.x - off] : 0;
        __syncthreads();
        s[threadIdx.x] += t;
        __syncthreads();
    }
    if (threadIdx.x < nbuck) {
        int b = s[threadIdx.x] - v;   // exclusive
        base[threadIdx.x] = b;
        gcur[threadIdx.x] = b;
    }
    if (threadIdx.x == 0) base[nbuck] = total;
}

// ---------------- pass B: partition edges into buckets ----------------
// staged word: (src << 8) | (dst & 255)
__global__ __launch_bounds__(256) void partition_kernel(const int* __restrict__ src,
                                                        const int* __restrict__ dst,
                                                        int* __restrict__ gcur,
                                                        unsigned int* __restrict__ bucketed,
                                                        int n_edges, int nbuck) {
    __shared__ int cnt[512];
    __shared__ int base[512];
    const int t = threadIdx.x;
    for (int i = t; i < 512; i += 256) cnt[i] = 0;
    __syncthreads();
    long long start = (long long)blockIdx.x * PART_CHUNK;
    int sv[16], dv[16], bv[16];
#pragma unroll
    for (int k = 0; k < 16; ++k) {
        long long e = start + (long long)k * 256 + t;
        bool ok = e < n_edges;
        sv[k] = ok ? src[e] : 0;
        dv[k] = ok ? dst[e] : 0;
        bv[k] = ok ? (dv[k] >> NBUCK_SHIFT) : -1;
        if (ok) atomicAdd(&cnt[bv[k]], 1);
    }
    __syncthreads();
    for (int i = t; i < nbuck; i += 256) {
        int c = cnt[i];
        base[i] = c ? atomicAdd(&gcur[i], c) : 0;
    }
    __syncthreads();
    for (int i = t; i < 512; i += 256) cnt[i] = 0;   // reuse as running cursor
    __syncthreads();
#pragma unroll
    for (int k = 0; k < 16; ++k) {
        if (bv[k] >= 0) {
            int pos = base[bv[k]] + atomicAdd(&cnt[bv[k]], 1);
            bucketed[pos] = ((unsigned int)sv[k] << 8) | (unsigned int)(dv[k] & 255);
        }
    }
}

// ---------------- pass C: per-bucket CSR finalize ----------------
__global__ __launch_bounds__(256) void csr_kernel(const unsigned int* __restrict__ bucketed,
                                                  const int* __restrict__ base,
                                                  int* __restrict__ offsets,
                                                  float* __restrict__ dinv,
                                                  int* __restrict__ sorted_src,
                                                  int n, int n_edges) {
    __shared__ int ldeg[256];
    __shared__ int lscan[256];
    const int b = blockIdx.x;
    const int t = threadIdx.x;
    const int beg = base[b], end = base[b + 1];
    ldeg[t] = 0;
    __syncthreads();
    for (int e = beg + t; e < end; e += 256) {
        unsigned int p = bucketed[e];
        atomicAdd(&ldeg[p & 255u], 1);
    }
    __syncthreads();
    int v = ldeg[t];
    lscan[t] = v;
    __syncthreads();
    for (int off = 1; off < 256; off <<= 1) {
        int x = (t >= off) ? lscan[t - off] : 0;
        __syncthreads();
        lscan[t] += x;
        __syncthreads();
    }
    int excl = lscan[t] - v;                         // exclusive scan
    int node = (b << NBUCK_SHIFT) + t;
    if (node < n) {
        offsets[node] = beg + excl;
        dinv[node]    = rsqrtf((float)v + 1.0f);     // +1 self-loop
    }
    if (b == 0 && t == 0) offsets[n] = n_edges;
    __syncthreads();
    lscan[t] = beg + excl;                           // reuse as placement cursor
    __syncthreads();
    for (int e = beg + t; e < end; e += 256) {
        unsigned int p = bucketed[e];
        int pos = atomicAdd(&lscan[p & 255u], 1);
        sorted_src[pos] = (int)(p >> 8);
    }
}

// ---------------- helpers ----------------
__device__ inline void acc8(float* acc, float4 raw) {
    const __half2* h2 = reinterpret_cast<const __half2*>(&raw);
#pragma unroll
    for (int j = 0; j < 4; ++j) {
        float2 v = __half22float2(h2[j]);
        acc[2 * j]     += v.x;
        acc[2 * j + 1] += v.y;
    }
}
__device__ inline float4 pack8(const float* v) {
    float4 out;
    __half2* h2 = reinterpret_cast<__half2*>(&out);
#pragma unroll
    for (int j = 0; j < 4; ++j) h2[j] = __floats2half2_rn(v[2 * j], v[2 * j + 1]);
    return out;
}

// ---------------- xs[node, 0..23] = half(x[node,0..17] * dinv[node]), padded --
__global__ __launch_bounds__(256) void scale_pad18_kernel(const float* __restrict__ x,
                                                          const float* __restrict__ dinv,
                                                          __half* __restrict__ xs, int n) {
    int node = blockIdx.x * 256 + threadIdx.x;
    if (node >= n) return;
    float di = dinv[node];
    const float* xr = x + (long long)node * 18;
    float v[24];
#pragma unroll
    for (int k = 0; k < 18; ++k) v[k] = xr[k] * di;
#pragma unroll
    for (int k = 18; k < 24; ++k) v[k] = 0.0f;
    float4* o = reinterpret_cast<float4*>(xs + (long long)node * 24);
    o[0] = pack8(v);
    o[1] = pack8(v + 8);
    o[2] = pack8(v + 16);
}

// ---------------- gather24: pure gather of xs (18 used dims), fp32 out -------
// 4 lanes/node edge-split; butterfly all-reduce; lanes 0..2 store 8 floats each
// into aggx row (stride 32 floats; dims 24..31 unused).
__global__ __launch_bounds__(256) void gather24_kernel(
    const __half* __restrict__ xs,
    const int* __restrict__ sorted_src, const int* __restrict__ offsets,
    float* __restrict__ aggx, int n) {
    long long gt = (long long)blockIdx.x * 256 + threadIdx.x;
    int node = (int)(gt >> 2);
    int l4   = (int)(gt & 3);
    if (node >= n) return;
    int beg = offsets[node], end = offsets[node + 1];

    float acc[24];
#pragma unroll
    for (int j = 0; j < 24; ++j) acc[j] = 0.0f;
    if (l4 == 3) {
        const float4* pp = reinterpret_cast<const float4*>(xs + (long long)node * 24);
        acc8(acc, pp[0]); acc8(acc + 8, pp[1]); acc8(acc + 16, pp[2]);
    }
    for (int e = beg + l4; e < end; e += 4) {
        int s = sorted_src[e];
        const float4* pp = reinterpret_cast<const float4*>(xs + (long long)s * 24);
        acc8(acc, pp[0]); acc8(acc + 8, pp[1]); acc8(acc + 16, pp[2]);
    }
#pragma unroll
    for (int j = 0; j < 24; ++j) {
        acc[j] += __shfl_xor(acc[j], 1);
        acc[j] += __shfl_xor(acc[j], 2);
    }
    if (l4 < 3) {
        float4* o = reinterpret_cast<float4*>(aggx + (long long)node * 32 + l4 * 8);
        o[0] = make_float4(acc[l4 * 8 + 0], acc[l4 * 8 + 1], acc[l4 * 8 + 2], acc[l4 * 8 + 3]);
        o[1] = make_float4(acc[l4 * 8 + 4], acc[l4 * 8 + 5], acc[l4 * 8 + 6], acc[l4 * 8 + 7]);
    }
}

// ---------------- dense12: (aggx*di)@W1+b1, relu, @W2, *di -> h2s fp16 -------
// 1 lane/node; W1/b1/W2 at wave-uniform addresses -> SGPR operands, no LDS.
__global__ __launch_bounds__(256) void dense12_kernel(
    const float* __restrict__ aggx, const float* __restrict__ dinv,
    const float* __restrict__ W1, const float* __restrict__ b1,
    const float* __restrict__ W2, __half* __restrict__ h2s, int n) {
    int node = blockIdx.x * 256 + threadIdx.x;
    if (node >= n) return;
    float di = dinv[node];
    const float4* ar = reinterpret_cast<const float4*>(aggx + (long long)node * 32);
    float a[24];
#pragma unroll
    for (int q = 0; q < 6; ++q) {
        float4 v = ar[q];
        a[4 * q] = v.x; a[4 * q + 1] = v.y; a[4 * q + 2] = v.z; a[4 * q + 3] = v.w;
    }
    float hidden[64];
#pragma unroll
    for (int j = 0; j < 64; ++j) hidden[j] = b1[j];
#pragma unroll
    for (int k = 0; k < 18; ++k) {
        float v = a[k] * di;
#pragma unroll
        for (int j = 0; j < 64; ++j) hidden[j] = fmaf(v, W1[k * 64 + j], hidden[j]);
    }
#pragma unroll
    for (int j = 0; j < 64; ++j) hidden[j] = fmaxf(hidden[j], 0.0f);

    float out[32];
#pragma unroll
    for (int f = 0; f < 32; ++f) out[f] = 0.0f;
#pragma unroll
    for (int j = 0; j < 64; ++j) {
        float v = hidden[j];
#pragma unroll
        for (int f = 0; f < 32; ++f) out[f] = fmaf(v, W2[j * 32 + f], out[f]);
    }
#pragma unroll
    for (int f = 0; f < 32; ++f) out[f] *= di;

    float4* o = reinterpret_cast<float4*>(h2s + (long long)node * 32);
    o[0] = pack8(out);
    o[1] = pack8(out + 8);
    o[2] = pack8(out + 16);
    o[3] = pack8(out + 24);
}

// ---------------- gather32: pure gather of h2s, fp32 out ---------------------
// 4 lanes/node edge-split; reduce-scatter -> each lane owns 8 dims, stores.
__global__ __launch_bounds__(256) void gather32_kernel(
    const __half* __restrict__ h2s,
    const int* __restrict__ sorted_src, const int* __restrict__ offsets,
    float* __restrict__ agg2, int n) {
    long long gt = (long long)blockIdx.x * 256 + threadIdx.x;
    int node = (int)(gt >> 2);
    int l4   = (int)(gt & 3);
    if (node >= n) return;
    int beg = offsets[node], end = offsets[node + 1];

    float acc[32];
#pragma unroll
    for (int j = 0; j < 32; ++j) acc[j] = 0.0f;
    if (l4 == 3) {
        const float4* pp = reinterpret_cast<const float4*>(h2s + (long long)node * 32);
        acc8(acc, pp[0]); acc8(acc + 8, pp[1]); acc8(acc + 16, pp[2]); acc8(acc + 24, pp[3]);
    }
    for (int e = beg + l4; e < end; e += 4) {
        int s = sorted_src[e];
        const float4* pp = reinterpret_cast<const float4*>(h2s + (long long)s * 32);
        acc8(acc, pp[0]); acc8(acc + 8, pp[1]); acc8(acc + 16, pp[2]); acc8(acc + 24, pp[3]);
    }
    // reduce-scatter acc[32] -> lane owns [8*l4, 8*l4+8)
    const bool hi2 = (l4 & 2);
    float h16[16];
#pragma unroll
    for (int v = 0; v < 16; ++v) {
        float keep = hi2 ? acc[16 + v] : acc[v];
        float send = hi2 ? acc[v] : acc[16 + v];
        h16[v] = keep + __shfl_xor(send, 2);
    }
    const bool hi1 = (l4 & 1);
    float k8[8];
#pragma unroll
    for (int v = 0; v < 8; ++v) {
        float keep = hi1 ? h16[8 + v] : h16[v];
        float send = hi1 ? h16[v] : h16[8 + v];
        k8[v] = keep + __shfl_xor(send, 1);
    }
    float4* o = reinterpret_cast<float4*>(agg2 + (long long)node * 32 + l4 * 8);
    o[0] = make_float4(k8[0], k8[1], k8[2], k8[3]);
    o[1] = make_float4(k8[4], k8[5], k8[6], k8[7]);
}

// ---------------- dense3: relu(agg2*di + b2) @ W3, *di -> h3s fp16 -----------
__global__ __launch_bounds__(256) void dense3_kernel(
    const float* __restrict__ agg2, const float* __restrict__ dinv,
    const float* __restrict__ b2, const float* __restrict__ W3,
    __half* __restrict__ h3s, int n) {
    int node = blockIdx.x * 256 + threadIdx.x;
    if (node >= n) return;
    float di = dinv[node];
    const float4* ar = reinterpret_cast<const float4*>(agg2 + (long long)node * 32);
    float a[32];
#pragma unroll
    for (int q = 0; q < 8; ++q) {
        float4 v = ar[q];
        a[4 * q] = v.x; a[4 * q + 1] = v.y; a[4 * q + 2] = v.z; a[4 * q + 3] = v.w;
    }
    float out[16];
#pragma unroll
    for (int f = 0; f < 16; ++f) out[f] = 0.0f;
#pragma unroll
    for (int k = 0; k < 32; ++k) {
        float v = fmaxf(fmaf(a[k], di, b2[k]), 0.0f);
#pragma unroll
        for (int f = 0; f < 16; ++f) out[f] = fmaf(v, W3[k * 16 + f], out[f]);
    }
#pragma unroll
    for (int f = 0; f < 16; ++f) out[f] *= di;
    float4* o = reinterpret_cast<float4*>(h3s + (long long)node * 16);
    o[0] = pack8(out);
    o[1] = pack8(out + 8);
}

// ---------------- fused layer 4 (4 lanes/node, tiny weights) -----------------
__global__ __launch_bounds__(256) void layer4_kernel(
    const __half* __restrict__ h3s, const float* __restrict__ dinv,
    const int* __restrict__ sorted_src, const int* __restrict__ offsets,
    const float* __restrict__ b3, const float* __restrict__ W4,
    __half* __restrict__ h4s, int n) {
    __shared__ float sW4[32];
    __shared__ float sB3[16];
    for (int i = threadIdx.x; i < 32; i += 256) sW4[i] = W4[i];
    for (int i = threadIdx.x; i < 16; i += 256) sB3[i] = b3[i];
    __syncthreads();

    long long gt = (long long)blockIdx.x * 256 + threadIdx.x;
    int node = (int)(gt >> 2);
    int l4   = (int)(gt & 3);
    if (node >= n) return;
    int beg = offsets[node], end = offsets[node + 1];
    float di = dinv[node];

    float acc[16];
#pragma unroll
    for (int j = 0; j < 16; ++j) acc[j] = 0.0f;
    if (l4 == 3) {
        const float4* pp = reinterpret_cast<const float4*>(h3s + (long long)node * 16);
        acc8(acc, pp[0]); acc8(acc + 8, pp[1]);
    }
    for (int e = beg + l4; e < end; e += 4) {
        int s = sorted_src[e];
        const float4* pp = reinterpret_cast<const float4*>(h3s + (long long)s * 16);
        acc8(acc, pp[0]); acc8(acc + 8, pp[1]);
    }
    const bool hi2 = (l4 & 2);
    float h8[8];
#pragma unroll
    for (int v = 0; v < 8; ++v) {
        float keep = hi2 ? acc[8 + v] : acc[v];
        float send = hi2 ? acc[v] : acc[8 + v];
        h8[v] = keep + __shfl_xor(send, 2);
    }
    const bool hi1 = (l4 & 1);
    float k4[4];
#pragma unroll
    for (int v = 0; v < 4; ++v) {
        float keep = hi1 ? h8[4 + v] : h8[v];
        float send = hi1 ? h8[v] : h8[4 + v];
        k4[v] = keep + __shfl_xor(send, 1);
    }
    const int k0 = l4 * 4;
    float o0 = 0.0f, o1 = 0.0f;
#pragma unroll
    for (int kk = 0; kk < 4; ++kk) {
        float v = fmaxf(fmaf(k4[kk], di, sB3[k0 + kk]), 0.0f);
        o0 = fmaf(v, sW4[2 * (k0 + kk)], o0);
        o1 = fmaf(v, sW4[2 * (k0 + kk) + 1], o1);
    }
    o0 += __shfl_xor(o0, 1); o0 += __shfl_xor(o0, 2);
    o1 += __shfl_xor(o1, 1); o1 += __shfl_xor(o1, 2);
    if (l4 == 0)
        *reinterpret_cast<__half2*>(h4s + 2LL * node) = __floats2half2_rn(o0 * di, o1 * di);
}

// ---------------- final: F=2 aggregation + log_softmax (4 lanes/node) --------
__global__ __launch_bounds__(256) void agg2_lsm_kernel(
    const __half* __restrict__ hs, const float* __restrict__ dinv,
    const int* __restrict__ sorted_src, const int* __restrict__ offsets,
    const float* __restrict__ b, float* __restrict__ out, int n) {
    long long gt = (long long)blockIdx.x * 256 + threadIdx.x;
    int node = (int)(gt >> 2);
    int l4   = (int)(gt & 3);
    if (node >= n) return;
    int beg = offsets[node], end = offsets[node + 1];
    float ax = 0.0f, ay = 0.0f;
    if (l4 == 3) {
        float2 r = __half22float2(*reinterpret_cast<const __half2*>(hs + 2LL * node));
        ax += r.x; ay += r.y;
    }
    for (int e = beg + l4; e < end; e += 4) {
        int s = sorted_src[e];
        float2 r = __half22float2(*reinterpret_cast<const __half2*>(hs + 2LL * s));
        ax += r.x; ay += r.y;
    }
    ax += __shfl_xor(ax, 1); ax += __shfl_xor(ax, 2);
    ay += __shfl_xor(ay, 1); ay += __shfl_xor(ay, 2);
    if (l4 == 0) {
        float di = dinv[node];
        float a = ax * di + b[0];
        float c = ay * di + b[1];
        float m = fmaxf(a, c);
        float lse = m + logf(expf(a - m) + expf(c - m));
        float2 r = make_float2(a - lse, c - lse);
        *reinterpret_cast<float2*>(out + 2LL * node) = r;
    }
}

static inline int cdiv_ll(long long a, int b) { return (int)((a + b - 1) / b); }
static inline char* align16(char* p) { return (char*)(((uintptr_t)p + 15) & ~(uintptr_t)15); }

extern "C" void kernel_launch(void* const* d_in, const int* in_sizes, int n_in,
                              void* d_out, int out_size, void* d_ws, size_t ws_size,
                              hipStream_t stream) {
    (void)n_in; (void)out_size; (void)ws_size;

    const float* x  = (const float*)d_in[0];      // [N,18]
    const int*   ei = (const int*)d_in[1];        // [2,E]
    const float* W1 = (const float*)d_in[2];
    const float* b1 = (const float*)d_in[3];
    const float* W2 = (const float*)d_in[4];
    const float* b2 = (const float*)d_in[5];
    const float* W3 = (const float*)d_in[6];
    const float* b3 = (const float*)d_in[7];
    const float* W4 = (const float*)d_in[8];
    const float* b4 = (const float*)d_in[9];

    const int n = in_sizes[0] / 18;               // 100000
    const int E = in_sizes[1] / 2;                // 1600000
    const int* src = ei;
    const int* dst = ei + E;
    const int nbuck = (n + 255) >> NBUCK_SHIFT;   // 391

    // ---- workspace layout (16B-aligned regions) ----
    char* p = (char*)d_ws;
    int*    hist       = (int*)p;            p = align16(p + 512 * 4);
    int*    bbase      = (int*)p;            p = align16(p + 512 * 4);
    int*    gcur       = (int*)p;            p = align16(p + 512 * 4);
    int*    offsets    = (int*)p;            p = align16(p + (size_t)(n + 1) * 4);
    float*  dinv       = (float*)p;          p = align16(p + (size_t)n * 4);
    int*    sorted_src = (int*)p;            p = align16(p + (size_t)E * 4);
    unsigned int* bucketed = (unsigned int*)p; p = align16(p + (size_t)E * 4);
    __half* xs         = (__half*)p;         p = align16(p + (size_t)n * 24 * 2);  // 4.8MB
    __half* h2s        = (__half*)p;         p = align16(p + (size_t)n * 32 * 2);  // 6.4MB
    __half* h3s        = (__half*)p;         p = align16(p + (size_t)n * 16 * 2);  // 3.2MB
    __half* h4s        = (__half*)p;         p = align16(p + (size_t)n * 2 * 2);   // 0.4MB
    float*  aggbuf     = (float*)p;          p = align16(p + (size_t)n * 32 * 4);  // 12.8MB (aggx, then agg2)

    const int B = 256;
    const int NODE_BLOCKS  = cdiv_ll(n, B);
    const int NODE4_BLOCKS = cdiv_ll(4LL * n, B);

    // ---- CSR-by-dst via bucketed counting sort ----
    hipMemsetAsync(hist, 0, 512 * 4, stream);
    hist_kernel<<<512, B, 0, stream>>>(dst, hist, E, nbuck);
    scan_hist_kernel<<<1, 512, 0, stream>>>(hist, bbase, gcur, nbuck, E);
    partition_kernel<<<cdiv_ll(E, PART_CHUNK), B, 0, stream>>>(src, dst, gcur, bucketed, E, nbuck);
    csr_kernel<<<nbuck, B, 0, stream>>>(bucketed, bbase, offsets, dinv, sorted_src, n, E);

    // ---- layers 1+2: gather (pure) then dense (pure) ----
    scale_pad18_kernel<<<NODE_BLOCKS, B, 0, stream>>>(x, dinv, xs, n);
    gather24_kernel<<<NODE4_BLOCKS, B, 0, stream>>>(xs, sorted_src, offsets, aggbuf, n);
    dense12_kernel<<<NODE_BLOCKS, B, 0, stream>>>(aggbuf, dinv, W1, b1, W2, h2s, n);

    // ---- layer 3: gather then dense ----
    gather32_kernel<<<NODE4_BLOCKS, B, 0, stream>>>(h2s, sorted_src, offsets, aggbuf, n);
    dense3_kernel<<<NODE_BLOCKS, B, 0, stream>>>(aggbuf, dinv, b2, W3, h3s, n);

    // ---- layer 4 (fused, tiny) + final aggregation/log_softmax ----
    layer4_kernel<<<NODE4_BLOCKS, B, 0, stream>>>(h3s, dinv, sorted_src, offsets, b3, W4, h4s, n);
    agg2_lsm_kernel<<<NODE4_BLOCKS, B, 0, stream>>>(h4s, dinv, sorted_src, offsets, b4, (float*)d_out, n);
}